// Round 16
// baseline (858.238 us; speedup 1.0000x reference)
//
#include <hip/hip_runtime.h>
#include <math.h>

#define PPB 2048
#define NBATCH 8
#define KNN 20

typedef __attribute__((ext_vector_type(8))) short short8;
typedef __attribute__((ext_vector_type(8))) __bf16 bf16x8;
typedef __attribute__((ext_vector_type(4))) float f32x4;

// ---------------------------------------------------------------------------
// feats GEMM with split-K=4 (fallback when ws too small for nz=8)
// ---------------------------------------------------------------------------
__global__ __launch_bounds__(256) void gemm_feats_kernel(
    const float* __restrict__ X, const float* __restrict__ W,
    float* __restrict__ fpart, int N) {
  const int KC = 336;
  int kc = blockIdx.z;
  const float* Xp = X + kc * KC;
  const float* Wp = W + kc * KC;
  float* Y = fpart + (size_t)kc * N * 128;
  __shared__ float Xs[8][132];
  __shared__ float Ws[8][132];
  int t = threadIdx.x;
  int tx = t & 15, ty = t >> 4;
  int i0 = blockIdx.y * 128;
  float acc[8][8];
#pragma unroll
  for (int r = 0; r < 8; ++r)
#pragma unroll
    for (int n = 0; n < 8; ++n) acc[r][n] = 0.f;

  for (int k0 = 0; k0 < KC; k0 += 8) {
#pragma unroll
    for (int p = 0; p < 4; ++p) {
      int e = t + p * 256, r = e >> 3, c = e & 7, k = k0 + c;
      Xs[c][r] = Xp[(size_t)(i0 + r) * 1344 + k];
      Ws[c][r] = Wp[(size_t)r * 1344 + k];
    }
    __syncthreads();
#pragma unroll
    for (int k = 0; k < 8; ++k) {
      float4 a0 = *(const float4*)&Xs[k][ty * 8];
      float4 a1 = *(const float4*)&Xs[k][ty * 8 + 4];
      float a[8] = {a0.x, a0.y, a0.z, a0.w, a1.x, a1.y, a1.z, a1.w};
      float4 b0 = *(const float4*)&Ws[k][tx * 8];
      float4 b1 = *(const float4*)&Ws[k][tx * 8 + 4];
      float bb[8] = {b0.x, b0.y, b0.z, b0.w, b1.x, b1.y, b1.z, b1.w};
#pragma unroll
      for (int r = 0; r < 8; ++r)
#pragma unroll
        for (int n = 0; n < 8; ++n) acc[r][n] += a[r] * bb[n];
    }
    __syncthreads();
  }
#pragma unroll
  for (int r = 0; r < 8; ++r) {
    size_t row = (size_t)(i0 + ty * 8 + r) * 128 + tx * 8;
#pragma unroll
    for (int n4 = 0; n4 < 2; ++n4) {
      float4 o;
      o.x = acc[r][n4 * 4 + 0]; o.y = acc[r][n4 * 4 + 1];
      o.z = acc[r][n4 * 4 + 2]; o.w = acc[r][n4 * 4 + 3];
      *(float4*)&Y[row + n4 * 4] = o;
    }
  }
}

__global__ __launch_bounds__(256) void reduce_feats_kernel(
    const float* __restrict__ fpart, const float* __restrict__ bias,
    float* __restrict__ catbuf, int N) {
  int e = blockIdx.x * 256 + threadIdx.x;
  size_t NP = (size_t)N * 128;
  int i = e >> 7, m = e & 127;
  float s = bias[m] + fpart[e] + fpart[NP + e] + fpart[2 * NP + e] + fpart[3 * NP + e];
  catbuf[(size_t)i * 576 + 448 + m] = s;
}

// ---------------------------------------------------------------------------
// feats via bf16 MFMA hi/lo 3-pass
// ---------------------------------------------------------------------------
__global__ __launch_bounds__(256) void feats_mfma_kernel(
    const unsigned short* __restrict__ Xh, const unsigned short* __restrict__ Xl,
    const unsigned short* __restrict__ Wh, const unsigned short* __restrict__ Wl,
    const float* __restrict__ bias, float* __restrict__ catbuf) {
  __shared__ unsigned short XsH[64][40], XsL[64][40];
  __shared__ unsigned short WsH[64][40], WsL[64][40];
  int t = threadIdx.x;
  int l = t & 63, w = t >> 6;
  int i0 = blockIdx.y * 64, m0 = blockIdx.x * 64;
  int r_st = t >> 2, c_st = (t & 3) * 8;

  f32x4 acc[4];
#pragma unroll
  for (int g = 0; g < 4; ++g) acc[g] = (f32x4){0.f, 0.f, 0.f, 0.f};

  for (int k0 = 0; k0 < 1344; k0 += 32) {
    short8 xh = *(const short8*)&Xh[(size_t)(i0 + r_st) * 1344 + k0 + c_st];
    short8 xl = *(const short8*)&Xl[(size_t)(i0 + r_st) * 1344 + k0 + c_st];
    short8 wh = *(const short8*)&Wh[(size_t)(m0 + r_st) * 1344 + k0 + c_st];
    short8 wl = *(const short8*)&Wl[(size_t)(m0 + r_st) * 1344 + k0 + c_st];
    __syncthreads();
    *(short8*)&XsH[r_st][c_st] = xh;
    *(short8*)&XsL[r_st][c_st] = xl;
    *(short8*)&WsH[r_st][c_st] = wh;
    *(short8*)&WsL[r_st][c_st] = wl;
    __syncthreads();
    bf16x8 ah = __builtin_bit_cast(bf16x8, *(const short8*)&XsH[16 * w + (l & 15)][(l >> 4) * 8]);
    bf16x8 al = __builtin_bit_cast(bf16x8, *(const short8*)&XsL[16 * w + (l & 15)][(l >> 4) * 8]);
#pragma unroll
    for (int g = 0; g < 4; ++g) {
      bf16x8 bh = __builtin_bit_cast(bf16x8, *(const short8*)&WsH[g * 16 + (l & 15)][(l >> 4) * 8]);
      bf16x8 bl = __builtin_bit_cast(bf16x8, *(const short8*)&WsL[g * 16 + (l & 15)][(l >> 4) * 8]);
      acc[g] = __builtin_amdgcn_mfma_f32_16x16x32_bf16(ah, bh, acc[g], 0, 0, 0);
      acc[g] = __builtin_amdgcn_mfma_f32_16x16x32_bf16(ah, bl, acc[g], 0, 0, 0);
      acc[g] = __builtin_amdgcn_mfma_f32_16x16x32_bf16(al, bh, acc[g], 0, 0, 0);
    }
  }
  int qr = (l >> 4) * 4;
#pragma unroll
  for (int g = 0; g < 4; ++g) {
    int col = m0 + g * 16 + (l & 15);
    float bv = bias[col];
#pragma unroll
    for (int r = 0; r < 4; ++r) {
      int row = i0 + w * 16 + qr + r;
      catbuf[(size_t)row * 576 + 448 + col] = acc[g][r] + bv;
    }
  }
}

// ---------------------------------------------------------------------------
// Fused EdgeConv A/Pb GEMM
// ---------------------------------------------------------------------------
__global__ __launch_bounds__(256) void edge_gemm_kernel(
    const float* __restrict__ X, int ldx, int D,
    const float* __restrict__ W, int ldw, int M,
    float* __restrict__ A, float* __restrict__ Pb) {
  __shared__ float Xs[16][68];
  __shared__ float Ws[16][68];
  int t = threadIdx.x, tx = t & 15, ty = t >> 4;
  int nHalf = M >> 6;
  int mt = blockIdx.x;
  int is_b = (mt >= nHalf) ? 1 : 0;
  int m0 = (is_b ? mt - nHalf : mt) << 6;
  int koff = is_b ? D : 0;
  float* __restrict__ out = is_b ? Pb : A;
  int i0 = blockIdx.y * 64;
  float acc[4][4];
#pragma unroll
  for (int r = 0; r < 4; ++r)
#pragma unroll
    for (int n = 0; n < 4; ++n) acc[r][n] = 0.f;

  for (int k0 = 0; k0 < D; k0 += 16) {
#pragma unroll
    for (int p = 0; p < 4; ++p) {
      int e = t + p * 256, r = e >> 4, c = e & 15, k = k0 + c;
      Xs[c][r] = (k < D) ? X[(size_t)(i0 + r) * ldx + k] : 0.f;
      Ws[c][r] = (k < D) ? W[(size_t)(m0 + r) * ldw + koff + k] : 0.f;
    }
    __syncthreads();
#pragma unroll
    for (int kk = 0; kk < 16; ++kk) {
      float4 a4 = *(const float4*)&Xs[kk][ty * 4];
      float4 b4 = *(const float4*)&Ws[kk][tx * 4];
      float a[4] = {a4.x, a4.y, a4.z, a4.w};
      float bb[4] = {b4.x, b4.y, b4.z, b4.w};
#pragma unroll
      for (int r = 0; r < 4; ++r)
#pragma unroll
        for (int n = 0; n < 4; ++n) acc[r][n] += a[r] * bb[n];
    }
    __syncthreads();
  }
#pragma unroll
  for (int r = 0; r < 4; ++r) {
    float4 o;
    o.x = acc[r][0]; o.y = acc[r][1]; o.z = acc[r][2]; o.w = acc[r][3];
    *(float4*)&out[(size_t)(i0 + ty * 4 + r) * M + m0 + tx * 4] = o;
  }
}

// ---------------------------------------------------------------------------
// fp32 -> bf16 RNE cast
// ---------------------------------------------------------------------------
__global__ __launch_bounds__(256) void cast_bf16_kernel(
    const float* __restrict__ src, unsigned short* __restrict__ dst, int n) {
  int e4 = (blockIdx.x * 256 + threadIdx.x) * 4;
  if (e4 >= n) return;
  float4 v = *(const float4*)&src[e4];
  ushort4 o;
  unsigned int u;
  u = __float_as_uint(v.x); o.x = (unsigned short)((u + 0x7fff + ((u >> 16) & 1)) >> 16);
  u = __float_as_uint(v.y); o.y = (unsigned short)((u + 0x7fff + ((u >> 16) & 1)) >> 16);
  u = __float_as_uint(v.z); o.z = (unsigned short)((u + 0x7fff + ((u >> 16) & 1)) >> 16);
  u = __float_as_uint(v.w); o.w = (unsigned short)((u + 0x7fff + ((u >> 16) & 1)) >> 16);
  *(ushort4*)&dst[e4] = o;
}

// ---------------------------------------------------------------------------
// hi/lo bf16 split cast + fused sq per row.
// ---------------------------------------------------------------------------
__global__ __launch_bounds__(256) void cast_hl_kernel(
    const float* __restrict__ X, int ldx, int D, int Kp,
    unsigned short* __restrict__ hi, unsigned short* __restrict__ lo,
    float* __restrict__ sq) {
  __shared__ float red[256];
  int i = blockIdx.x;
  int t = threadIdx.x;
  float s = 0.f;
  for (int k = t; k < Kp; k += 256) {
    float x = (k < D) ? X[(size_t)i * ldx + k] : 0.f;
    unsigned int u = __float_as_uint(x);
    unsigned short h = (unsigned short)((u + 0x7fff + ((u >> 16) & 1)) >> 16);
    float hf = __uint_as_float((unsigned int)h << 16);
    float r = x - hf;
    unsigned int v = __float_as_uint(r);
    unsigned short l16 = (unsigned short)((v + 0x7fff + ((v >> 16) & 1)) >> 16);
    hi[(size_t)i * Kp + k] = h;
    lo[(size_t)i * Kp + k] = l16;
    s += x * x;
  }
  red[t] = s;
  __syncthreads();
  for (int off = 128; off > 0; off >>= 1) {
    if (t < off) red[t] += red[t + off];
    __syncthreads();
  }
  if (t == 0) sq[i] = red[0];
}

// ---------------------------------------------------------------------------
// dist_gemm3: dist_gemm2 + per-(row, 32-col-group) packed-u64 minima.
// Lanes sharing l>>4 hold one row's 64 cols (16 lanes x 4 cc); a 4-step
// shfl_xor butterfly (o<16 stays in-group) reduces each 32-col half
// (cc{0,1}, cc{2,3}).  minbuf[z][row][64]: key=(ordered dist)<<32 | col.
// ---------------------------------------------------------------------------
template <int KP>
__global__ __launch_bounds__(256) void dist_gemm3_kernel(
    const unsigned short* __restrict__ Xhi,
    const unsigned short* __restrict__ Xlo,
    const float* __restrict__ sq,
    float* __restrict__ dist,
    unsigned long long* __restrict__ minbuf, int zBase) {
  __shared__ unsigned short Ah[128][40];
  __shared__ unsigned short Al[128][40];
  __shared__ unsigned short Bh[64][40];
  __shared__ unsigned short Bl[64][40];
  int t = threadIdx.x;
  int l = t & 63, w = t >> 6;
  int z = blockIdx.z;
  size_t bbase = (size_t)(zBase + z) * PPB;
  int c0 = blockIdx.x * 64, q0 = blockIdx.y * 128;

  f32x4 acc[2][4];
#pragma unroll
  for (int qs = 0; qs < 2; ++qs)
#pragma unroll
    for (int cc = 0; cc < 4; ++cc) acc[qs][cc] = (f32x4){0.f, 0.f, 0.f, 0.f};

  for (int k0 = 0; k0 < KP; k0 += 32) {
    short8 sa[2][2];
#pragma unroll
    for (int p = 0; p < 2; ++p) {
      int e = t + p * 256, row = e >> 2, kg = e & 3;
      sa[p][0] = *(const short8*)&Xhi[(bbase + q0 + row) * KP + k0 + kg * 8];
      sa[p][1] = *(const short8*)&Xlo[(bbase + q0 + row) * KP + k0 + kg * 8];
    }
    int brow = t >> 2, bkg = t & 3;
    short8 sb0 = *(const short8*)&Xhi[(bbase + c0 + brow) * KP + k0 + bkg * 8];
    short8 sb1 = *(const short8*)&Xlo[(bbase + c0 + brow) * KP + k0 + bkg * 8];
    __syncthreads();
#pragma unroll
    for (int p = 0; p < 2; ++p) {
      int e = t + p * 256, row = e >> 2, kg = e & 3;
      *(short8*)&Ah[row][kg * 8] = sa[p][0];
      *(short8*)&Al[row][kg * 8] = sa[p][1];
    }
    *(short8*)&Bh[brow][bkg * 8] = sb0;
    *(short8*)&Bl[brow][bkg * 8] = sb1;
    __syncthreads();

    bf16x8 ah[2], al[2], bh[4], bl[4];
#pragma unroll
    for (int qs = 0; qs < 2; ++qs) {
      int row = w * 32 + qs * 16 + (l & 15);
      ah[qs] = __builtin_bit_cast(bf16x8, *(const short8*)&Ah[row][(l >> 4) * 8]);
      al[qs] = __builtin_bit_cast(bf16x8, *(const short8*)&Al[row][(l >> 4) * 8]);
    }
#pragma unroll
    for (int cc = 0; cc < 4; ++cc) {
      bh[cc] = __builtin_bit_cast(bf16x8, *(const short8*)&Bh[cc * 16 + (l & 15)][(l >> 4) * 8]);
      bl[cc] = __builtin_bit_cast(bf16x8, *(const short8*)&Bl[cc * 16 + (l & 15)][(l >> 4) * 8]);
    }
#pragma unroll
    for (int qs = 0; qs < 2; ++qs)
#pragma unroll
      for (int cc = 0; cc < 4; ++cc) {
        acc[qs][cc] = __builtin_amdgcn_mfma_f32_16x16x32_bf16(ah[qs], bh[cc], acc[qs][cc], 0, 0, 0);
        acc[qs][cc] = __builtin_amdgcn_mfma_f32_16x16x32_bf16(ah[qs], bl[cc], acc[qs][cc], 0, 0, 0);
        acc[qs][cc] = __builtin_amdgcn_mfma_f32_16x16x32_bf16(al[qs], bh[cc], acc[qs][cc], 0, 0, 0);
      }
  }
  float* dz = dist + (size_t)z * PPB * PPB;
  unsigned long long* mb = minbuf + (size_t)z * PPB * 64;
  float sqjv[4];
#pragma unroll
  for (int cc = 0; cc < 4; ++cc)
    sqjv[cc] = sq[bbase + c0 + cc * 16 + (l & 15)];
#pragma unroll
  for (int qs = 0; qs < 2; ++qs)
#pragma unroll
    for (int r = 0; r < 4; ++r) {
      int row = q0 + w * 32 + qs * 16 + (l >> 4) * 4 + r;
      float d[4];
#pragma unroll
      for (int cc = 0; cc < 4; ++cc) {
        d[cc] = sqjv[cc] - 2.f * acc[qs][cc][r];
        dz[(size_t)row * PPB + c0 + cc * 16 + (l & 15)] = d[cc];
      }
#pragma unroll
      for (int gh = 0; gh < 2; ++gh) {
        float v0 = d[gh * 2 + 0], v1 = d[gh * 2 + 1];
        int cA = c0 + (gh * 2 + 0) * 16 + (l & 15);
        int cB = c0 + (gh * 2 + 1) * 16 + (l & 15);
        float mv = v0; int mc = cA;
        if (v1 < mv) { mv = v1; mc = cB; }
        unsigned u = __float_as_uint(mv);
        unsigned k = u ^ (((int)u >> 31) | 0x80000000u);
        unsigned long long p = ((unsigned long long)k << 32) | (unsigned)mc;
#pragma unroll
        for (int o = 1; o < 16; o <<= 1) {
          unsigned long long q2 = __shfl_xor(p, o);
          if (q2 < p) p = q2;
        }
        if ((l & 15) == 0)
          mb[(size_t)row * 64 + (c0 >> 5) + gh] = p;
      }
    }
}

// ---------------------------------------------------------------------------
// knn_sel5: hierarchical selection.  One wave per row; lane l holds group
// l's packed-u64 min (from minbuf).  20x: 6-step u64 butterfly (exact
// lowest-j tie-break); winner lane re-reads its 32-float group from dist
// with removal bitmask and recomputes its min.  grid (PPB/4, nz).
// ---------------------------------------------------------------------------
__global__ __launch_bounds__(256) void knn_sel5_kernel(
    const float* __restrict__ dist,
    const unsigned long long* __restrict__ minbuf,
    int zBase, int* __restrict__ idx) {
  int z = blockIdx.y;
  int b = zBase + z;
  int q = blockIdx.x * 4 + (threadIdx.x >> 6);
  int l = threadIdx.x & 63;
  const float* drow = dist + ((size_t)z * PPB + q) * PPB;
  unsigned long long P = minbuf[((size_t)z * PPB + q) * 64 + l];
  unsigned rm = 0;
#pragma unroll
  for (int s = 0; s < KNN; ++s) {
    unsigned long long p = P;
#pragma unroll
    for (int o = 1; o < 64; o <<= 1) {
      unsigned long long t2 = __shfl_xor(p, o);
      if (t2 < p) p = t2;
    }
    unsigned j = (unsigned)p;  // batch-local col
    if (l == 0)
      idx[((size_t)b * PPB + q) * KNN + s] = b * PPB + (int)j;
    if ((j >> 5) == (unsigned)l) {
      rm |= 1u << (j & 31u);
      const float* gp = drow + l * 32;
      float mv = 1e38f; int mc = 0;
#pragma unroll
      for (int m4 = 0; m4 < 8; ++m4) {
        float4 f = *(const float4*)&gp[m4 * 4];
        float e0 = ((rm >> (m4 * 4 + 0)) & 1u) ? 1e38f : f.x;
        float e1 = ((rm >> (m4 * 4 + 1)) & 1u) ? 1e38f : f.y;
        float e2 = ((rm >> (m4 * 4 + 2)) & 1u) ? 1e38f : f.z;
        float e3 = ((rm >> (m4 * 4 + 3)) & 1u) ? 1e38f : f.w;
        if (e0 < mv) { mv = e0; mc = m4 * 4 + 0; }
        if (e1 < mv) { mv = e1; mc = m4 * 4 + 1; }
        if (e2 < mv) { mv = e2; mc = m4 * 4 + 2; }
        if (e3 < mv) { mv = e3; mc = m4 * 4 + 3; }
      }
      unsigned u = __float_as_uint(mv);
      unsigned k = u ^ (((int)u >> 31) | 0x80000000u);
      P = ((unsigned long long)k << 32) | (unsigned)(l * 32 + mc);
    }
  }
}

// ---------------------------------------------------------------------------
// fc1 (576 -> 1024) via bf16 MFMA, fused max over 64-point tile.
// ---------------------------------------------------------------------------
__global__ __launch_bounds__(256) void fc1max_mfma_kernel(
    const unsigned short* __restrict__ Xb, const unsigned short* __restrict__ Wb,
    const float* __restrict__ bias, float* __restrict__ partial) {
  __shared__ unsigned short Xs[64][40];
  __shared__ unsigned short Ws[64][40];
  __shared__ float red[4][64];
  int t = threadIdx.x;
  int l = t & 63, w = t >> 6;
  int b = blockIdx.z, pt = blockIdx.y;
  int i0 = b * PPB + pt * 64;
  int m0 = blockIdx.x * 64;
  int r_st = t >> 2;
  int c_st = (t & 3) * 8;

  f32x4 acc[4];
#pragma unroll
  for (int g = 0; g < 4; ++g) acc[g] = (f32x4){0.f, 0.f, 0.f, 0.f};

  for (int k0 = 0; k0 < 576; k0 += 32) {
    short8 xv = *(const short8*)&Xb[(size_t)(i0 + r_st) * 576 + k0 + c_st];
    short8 wv = *(const short8*)&Wb[(size_t)(m0 + r_st) * 576 + k0 + c_st];
    __syncthreads();
    *(short8*)&Xs[r_st][c_st] = xv;
    *(short8*)&Ws[r_st][c_st] = wv;
    __syncthreads();
    short8 ar = *(const short8*)&Xs[16 * w + (l & 15)][(l >> 4) * 8];
    bf16x8 av = __builtin_bit_cast(bf16x8, ar);
#pragma unroll
    for (int g = 0; g < 4; ++g) {
      short8 br = *(const short8*)&Ws[g * 16 + (l & 15)][(l >> 4) * 8];
      bf16x8 bv = __builtin_bit_cast(bf16x8, br);
      acc[g] = __builtin_amdgcn_mfma_f32_16x16x32_bf16(av, bv, acc[g], 0, 0, 0);
    }
  }
  float pm[4];
#pragma unroll
  for (int g = 0; g < 4; ++g) {
    float m = fmaxf(fmaxf(acc[g][0], acc[g][1]), fmaxf(acc[g][2], acc[g][3]));
    m = fmaxf(m, __shfl_xor(m, 16));
    m = fmaxf(m, __shfl_xor(m, 32));
    pm[g] = m;
  }
  if (l < 16) {
#pragma unroll
    for (int g = 0; g < 4; ++g) red[w][g * 16 + l] = pm[g];
  }
  __syncthreads();
  if (t < 64) {
    float mx = fmaxf(fmaxf(red[0][t], red[1][t]), fmaxf(red[2][t], red[3][t]));
    partial[((size_t)b * (PPB / 64) + pt) * 1024 + m0 + t] = mx + bias[m0 + t];
  }
}

__global__ __launch_bounds__(256) void gmax_kernel(
    const float* __restrict__ partial, float* __restrict__ g) {
  int b = blockIdx.y;
  int m = blockIdx.x * 256 + threadIdx.x;
  float mx = -INFINITY;
  for (int pt = 0; pt < PPB / 64; ++pt)
    mx = fmaxf(mx, partial[((size_t)b * (PPB / 64) + pt) * 1024 + m]);
  g[b * 1024 + m] = mx;
}

// ---------------------------------------------------------------------------
__global__ __launch_bounds__(192) void h0_kernel(
    const float* __restrict__ pos, const float* __restrict__ xin,
    const float* __restrict__ catbuf, float* __restrict__ h0) {
  int i = blockIdx.x;
  int d = threadIdx.x;
  if (d < 3)        h0[(size_t)i * 134 + d] = pos[i * 3 + d];
  else if (d < 6)   h0[(size_t)i * 134 + d] = xin[i * 3 + d - 3];
  else if (d < 134) h0[(size_t)i * 134 + d] = catbuf[(size_t)i * 576 + 448 + (d - 6)];
}

// ---------------------------------------------------------------------------
// EdgeConv epilogue
// ---------------------------------------------------------------------------
__global__ __launch_bounds__(256) void edge_out_kernel(
    const float* __restrict__ A, const float* __restrict__ Pb, int M,
    const float* __restrict__ bias, const int* __restrict__ idx,
    float* __restrict__ Y, int ldy) {
  int i = blockIdx.x;
  int t = threadIdx.x;
  __shared__ int nbs[KNN];
  if (t < KNN) nbs[t] = idx[(size_t)i * KNN + t];
  __syncthreads();
  for (int m = t; m < M; m += 256) {
    float mx = -INFINITY;
#pragma unroll
    for (int kk = 0; kk < KNN; ++kk)
      mx = fmaxf(mx, Pb[(size_t)nbs[kk] * M + m]);
    Y[(size_t)i * ldy + m] = A[(size_t)i * M + m] + bias[m] - Pb[(size_t)i * M + m] + mx;
  }
}

// ---------------------------------------------------------------------------
// mlp2: wave-per-output GEMV.
// ---------------------------------------------------------------------------
__global__ __launch_bounds__(256) void mlp2_kernel(
    const float* __restrict__ X, const float* __restrict__ W,
    const float* __restrict__ bias, float* __restrict__ Y,
    int D, int M, int do_relu) {
  int b = blockIdx.y;
  int m = blockIdx.x * 4 + (threadIdx.x >> 6);
  int lane = threadIdx.x & 63;
  const float* xr = X + (size_t)b * D;
  const float* wr = W + (size_t)m * D;
  float s = 0.f;
  for (int k = lane * 4; k < D; k += 256) {
    float4 xv = *(const float4*)&xr[k];
    float4 wv = *(const float4*)&wr[k];
    s += xv.x * wv.x + xv.y * wv.y + xv.z * wv.z + xv.w * wv.w;
  }
#pragma unroll
  for (int o = 32; o > 0; o >>= 1) s += __shfl_down(s, o);
  if (lane == 0) {
    s += bias[m];
    if (do_relu) s = fmaxf(s, 0.f);
    Y[(size_t)b * M + m] = s;
  }
}

// ---------------------------------------------------------------------------
// final2: wave-parallel 256->23 + log_softmax.
// ---------------------------------------------------------------------------
__global__ __launch_bounds__(256) void final2_kernel(
    const float* __restrict__ X, const float* __restrict__ W,
    const float* __restrict__ bias, float* __restrict__ out) {
  int b = blockIdx.x;
  int w = threadIdx.x >> 6, lane = threadIdx.x & 63;
  __shared__ float lg[23];
  const float* xr = X + (size_t)b * 256;
  float4 xv = *(const float4*)&xr[lane * 4];
  for (int c = w; c < 23; c += 4) {
    const float* wr = W + (size_t)c * 256;
    float4 wv = *(const float4*)&wr[lane * 4];
    float s = xv.x * wv.x + xv.y * wv.y + xv.z * wv.z + xv.w * wv.w;
#pragma unroll
    for (int o = 32; o > 0; o >>= 1) s += __shfl_down(s, o);
    if (lane == 0) lg[c] = s + bias[c];
  }
  __syncthreads();
  if (threadIdx.x == 0) {
    float mx = lg[0];
    for (int c = 1; c < 23; ++c) mx = fmaxf(mx, lg[c]);
    float s = 0.f;
    for (int c = 0; c < 23; ++c) s += expf(lg[c] - mx);
    float lse = mx + logf(s);
    for (int c = 0; c < 23; ++c) out[b * 23 + c] = lg[c] - lse;
  }
}

// ---------------------------------------------------------------------------

extern "C" void kernel_launch(void* const* d_in, const int* in_sizes, int n_in,
                              void* d_out, int out_size, void* d_ws, size_t ws_size,
                              hipStream_t stream) {
  const float* pos      = (const float*)d_in[0];
  const float* xin      = (const float*)d_in[1];
  const float* features = (const float*)d_in[2];
  const float* Wf   = (const float*)d_in[4];
  const float* bf   = (const float*)d_in[5];
  const float* W1   = (const float*)d_in[6];
  const float* b1   = (const float*)d_in[7];
  const float* W2   = (const float*)d_in[8];
  const float* b2   = (const float*)d_in[9];
  const float* W3   = (const float*)d_in[10];
  const float* b3   = (const float*)d_in[11];
  const float* Wfc1 = (const float*)d_in[12];
  const float* bfc1 = (const float*)d_in[13];
  const float* Wfa  = (const float*)d_in[14];
  const float* bfa  = (const float*)d_in[15];
  const float* Wfb  = (const float*)d_in[16];
  const float* bfb  = (const float*)d_in[17];
  const float* Wfc  = (const float*)d_in[18];
  const float* bfc  = (const float*)d_in[19];
  float* out = (float*)d_out;

  const int N = in_sizes[0] / 3;  // 16384

  char* base = (char*)d_ws;
  size_t off = 0;
  auto alloc = [&](size_t bytes) {
    void* p = base + off;
    off += (bytes + 255) & ~(size_t)255;
    return p;
  };
  float* catbuf  = (float*)alloc((size_t)N * 576 * 4);  // [x1|x2|x3|feats]
  float* h0      = (float*)alloc((size_t)N * 134 * 4);
  float* Abuf    = (float*)alloc((size_t)N * 256 * 4);
  float* Pbbuf   = (float*)alloc((size_t)N * 256 * 4);
  unsigned short* Xhi = (unsigned short*)alloc((size_t)N * 160 * 2);
  unsigned short* Xlo = (unsigned short*)alloc((size_t)N * 160 * 2);
  float* sqbuf   = (float*)alloc((size_t)N * 4);
  int*   idxbuf  = (int*)  alloc((size_t)N * KNN * 4);
  unsigned long long* minbuf =
      (unsigned long long*)alloc((size_t)NBATCH * PPB * 64 * 8);  // 8 MB
  float* partial = (float*)alloc((size_t)NBATCH * (PPB / 64) * 1024 * 4);
  float* g       = (float*)alloc((size_t)NBATCH * 1024 * 4);
  float* ga      = (float*)alloc((size_t)NBATCH * 512 * 4);
  float* gb      = (float*)alloc((size_t)NBATCH * 256 * 4);

  // dist chunking: nz=8 (r10 best).  Fallbacks keep correctness on small ws.
  const size_t distBatch = (size_t)PPB * PPB * 4;
  int nz;
  float* dist;
  if (ws_size >= off + 8 * distBatch + 256) {
    nz = 8;  dist = (float*)alloc(8 * distBatch);
  } else if (ws_size >= off + 4 * distBatch + 256) {
    nz = 4;  dist = (float*)alloc(4 * distBatch);
  } else {
    nz = 2;  dist = Abuf;
  }

  float* fpart = Abuf;
  unsigned short* catb16 = (unsigned short*)Abuf;
  unsigned short* Wb16   = (unsigned short*)h0;

  // 1. feats = features @ Wf.T + bf -> catbuf[:,448:576]
  if (nz == 8) {
    unsigned short* featHi = (unsigned short*)dist;
    unsigned short* featLo = featHi + (size_t)N * 1344;
    unsigned short* WfHi   = (unsigned short*)partial;
    unsigned short* WfLo   = WfHi + (size_t)128 * 1344;
    cast_hl_kernel<<<N, 256, 0, stream>>>(features, 1344, 1344, 1344,
                                          featHi, featLo, sqbuf);
    cast_hl_kernel<<<128, 256, 0, stream>>>(Wf, 1344, 1344, 1344,
                                            WfHi, WfLo, sqbuf);
    feats_mfma_kernel<<<dim3(2, N / 64), 256, 0, stream>>>(
        featHi, featLo, WfHi, WfLo, bf, catbuf);
  } else {
    gemm_feats_kernel<<<dim3(1, N / 128, 4), 256, 0, stream>>>(features, Wf, fpart, N);
    reduce_feats_kernel<<<(N * 128) / 256, 256, 0, stream>>>(fpart, bf, catbuf, N);
  }

  // 2. h0 = [pos | x | feats]
  h0_kernel<<<N, 192, 0, stream>>>(pos, xin, catbuf, h0);

  struct Layer {
    const float* Xin; int ldx; int D; int Kp;
    const float* W; int ldw;
    const float* bias; int M;
    float* Yout;
  };
  Layer L[3] = {
      {h0,          134, 134, 160, W1, 268, b1,  64, catbuf + 0},
      {catbuf + 0,  576,  64,  64, W2, 128, b2, 128, catbuf + 64},
      {catbuf + 64, 576, 128, 128, W3, 256, b3, 256, catbuf + 192},
  };

  for (int l = 0; l < 3; ++l) {
    cast_hl_kernel<<<N, 256, 0, stream>>>(L[l].Xin, L[l].ldx, L[l].D, L[l].Kp,
                                          Xhi, Xlo, sqbuf);
    for (int p = 0; p < NBATCH; p += nz) {
      if (L[l].Kp == 160)
        dist_gemm3_kernel<160><<<dim3(PPB / 64, PPB / 128, nz), 256, 0, stream>>>(
            Xhi, Xlo, sqbuf, dist, minbuf, p);
      else if (L[l].Kp == 64)
        dist_gemm3_kernel<64><<<dim3(PPB / 64, PPB / 128, nz), 256, 0, stream>>>(
            Xhi, Xlo, sqbuf, dist, minbuf, p);
      else
        dist_gemm3_kernel<128><<<dim3(PPB / 64, PPB / 128, nz), 256, 0, stream>>>(
            Xhi, Xlo, sqbuf, dist, minbuf, p);
      knn_sel5_kernel<<<dim3(PPB / 4, nz), 256, 0, stream>>>(
          dist, minbuf, p, idxbuf);
    }
    // fused A = X@Wa.T and Pb = X@Wb.T
    edge_gemm_kernel<<<dim3((2 * L[l].M) / 64, N / 64), 256, 0, stream>>>(
        L[l].Xin, L[l].ldx, L[l].D, L[l].W, L[l].ldw, L[l].M, Abuf, Pbbuf);
    edge_out_kernel<<<N, 256, 0, stream>>>(
        Abuf, Pbbuf, L[l].M, L[l].bias, idxbuf, L[l].Yout, 576);
  }

  // casts for fc1 (catbuf complete; Abuf/Pbbuf/h0 dead)
  cast_bf16_kernel<<<(N * 576) / 1024, 256, 0, stream>>>(catbuf, catb16, N * 576);
  cast_bf16_kernel<<<(1024 * 576) / 1024, 256, 0, stream>>>(Wfc1, Wb16, 1024 * 576);

  // fc1 + max over points (bf16 MFMA)
  fc1max_mfma_kernel<<<dim3(1024 / 64, PPB / 64, NBATCH), 256, 0, stream>>>(
      catb16, Wb16, bfc1, partial);
  gmax_kernel<<<dim3(1024 / 256, NBATCH), 256, 0, stream>>>(partial, g);

  // head MLP (wave-per-output GEMV)
  mlp2_kernel<<<dim3(512 / 4, NBATCH), 256, 0, stream>>>(g,  Wfa, bfa, ga, 1024, 512, 1);
  mlp2_kernel<<<dim3(256 / 4, NBATCH), 256, 0, stream>>>(ga, Wfb, bfb, gb, 512, 256, 1);
  final2_kernel<<<NBATCH, 256, 0, stream>>>(gb, Wfc, bfc, out);
}

// Round 17
// 652.866 us; speedup vs baseline: 1.3146x; 1.3146x over previous
//
#include <hip/hip_runtime.h>
#include <math.h>

#define PPB 2048
#define NBATCH 8
#define KNN 20

typedef __attribute__((ext_vector_type(8))) short short8;
typedef __attribute__((ext_vector_type(8))) __bf16 bf16x8;
typedef __attribute__((ext_vector_type(4))) float f32x4;

// ---------------------------------------------------------------------------
// feats GEMM with split-K=4 (fallback when ws too small for nz=8)
// ---------------------------------------------------------------------------
__global__ __launch_bounds__(256) void gemm_feats_kernel(
    const float* __restrict__ X, const float* __restrict__ W,
    float* __restrict__ fpart, int N) {
  const int KC = 336;
  int kc = blockIdx.z;
  const float* Xp = X + kc * KC;
  const float* Wp = W + kc * KC;
  float* Y = fpart + (size_t)kc * N * 128;
  __shared__ float Xs[8][132];
  __shared__ float Ws[8][132];
  int t = threadIdx.x;
  int tx = t & 15, ty = t >> 4;
  int i0 = blockIdx.y * 128;
  float acc[8][8];
#pragma unroll
  for (int r = 0; r < 8; ++r)
#pragma unroll
    for (int n = 0; n < 8; ++n) acc[r][n] = 0.f;

  for (int k0 = 0; k0 < KC; k0 += 8) {
#pragma unroll
    for (int p = 0; p < 4; ++p) {
      int e = t + p * 256, r = e >> 3, c = e & 7, k = k0 + c;
      Xs[c][r] = Xp[(size_t)(i0 + r) * 1344 + k];
      Ws[c][r] = Wp[(size_t)r * 1344 + k];
    }
    __syncthreads();
#pragma unroll
    for (int k = 0; k < 8; ++k) {
      float4 a0 = *(const float4*)&Xs[k][ty * 8];
      float4 a1 = *(const float4*)&Xs[k][ty * 8 + 4];
      float a[8] = {a0.x, a0.y, a0.z, a0.w, a1.x, a1.y, a1.z, a1.w};
      float4 b0 = *(const float4*)&Ws[k][tx * 8];
      float4 b1 = *(const float4*)&Ws[k][tx * 8 + 4];
      float bb[8] = {b0.x, b0.y, b0.z, b0.w, b1.x, b1.y, b1.z, b1.w};
#pragma unroll
      for (int r = 0; r < 8; ++r)
#pragma unroll
        for (int n = 0; n < 8; ++n) acc[r][n] += a[r] * bb[n];
    }
    __syncthreads();
  }
#pragma unroll
  for (int r = 0; r < 8; ++r) {
    size_t row = (size_t)(i0 + ty * 8 + r) * 128 + tx * 8;
#pragma unroll
    for (int n4 = 0; n4 < 2; ++n4) {
      float4 o;
      o.x = acc[r][n4 * 4 + 0]; o.y = acc[r][n4 * 4 + 1];
      o.z = acc[r][n4 * 4 + 2]; o.w = acc[r][n4 * 4 + 3];
      *(float4*)&Y[row + n4 * 4] = o;
    }
  }
}

__global__ __launch_bounds__(256) void reduce_feats_kernel(
    const float* __restrict__ fpart, const float* __restrict__ bias,
    float* __restrict__ catbuf, int N) {
  int e = blockIdx.x * 256 + threadIdx.x;
  size_t NP = (size_t)N * 128;
  int i = e >> 7, m = e & 127;
  float s = bias[m] + fpart[e] + fpart[NP + e] + fpart[2 * NP + e] + fpart[3 * NP + e];
  catbuf[(size_t)i * 576 + 448 + m] = s;
}

// ---------------------------------------------------------------------------
// feats via bf16 MFMA hi/lo 3-pass
// ---------------------------------------------------------------------------
__global__ __launch_bounds__(256) void feats_mfma_kernel(
    const unsigned short* __restrict__ Xh, const unsigned short* __restrict__ Xl,
    const unsigned short* __restrict__ Wh, const unsigned short* __restrict__ Wl,
    const float* __restrict__ bias, float* __restrict__ catbuf) {
  __shared__ unsigned short XsH[64][40], XsL[64][40];
  __shared__ unsigned short WsH[64][40], WsL[64][40];
  int t = threadIdx.x;
  int l = t & 63, w = t >> 6;
  int i0 = blockIdx.y * 64, m0 = blockIdx.x * 64;
  int r_st = t >> 2, c_st = (t & 3) * 8;

  f32x4 acc[4];
#pragma unroll
  for (int g = 0; g < 4; ++g) acc[g] = (f32x4){0.f, 0.f, 0.f, 0.f};

  for (int k0 = 0; k0 < 1344; k0 += 32) {
    short8 xh = *(const short8*)&Xh[(size_t)(i0 + r_st) * 1344 + k0 + c_st];
    short8 xl = *(const short8*)&Xl[(size_t)(i0 + r_st) * 1344 + k0 + c_st];
    short8 wh = *(const short8*)&Wh[(size_t)(m0 + r_st) * 1344 + k0 + c_st];
    short8 wl = *(const short8*)&Wl[(size_t)(m0 + r_st) * 1344 + k0 + c_st];
    __syncthreads();
    *(short8*)&XsH[r_st][c_st] = xh;
    *(short8*)&XsL[r_st][c_st] = xl;
    *(short8*)&WsH[r_st][c_st] = wh;
    *(short8*)&WsL[r_st][c_st] = wl;
    __syncthreads();
    bf16x8 ah = __builtin_bit_cast(bf16x8, *(const short8*)&XsH[16 * w + (l & 15)][(l >> 4) * 8]);
    bf16x8 al = __builtin_bit_cast(bf16x8, *(const short8*)&XsL[16 * w + (l & 15)][(l >> 4) * 8]);
#pragma unroll
    for (int g = 0; g < 4; ++g) {
      bf16x8 bh = __builtin_bit_cast(bf16x8, *(const short8*)&WsH[g * 16 + (l & 15)][(l >> 4) * 8]);
      bf16x8 bl = __builtin_bit_cast(bf16x8, *(const short8*)&WsL[g * 16 + (l & 15)][(l >> 4) * 8]);
      acc[g] = __builtin_amdgcn_mfma_f32_16x16x32_bf16(ah, bh, acc[g], 0, 0, 0);
      acc[g] = __builtin_amdgcn_mfma_f32_16x16x32_bf16(ah, bl, acc[g], 0, 0, 0);
      acc[g] = __builtin_amdgcn_mfma_f32_16x16x32_bf16(al, bh, acc[g], 0, 0, 0);
    }
  }
  int qr = (l >> 4) * 4;
#pragma unroll
  for (int g = 0; g < 4; ++g) {
    int col = m0 + g * 16 + (l & 15);
    float bv = bias[col];
#pragma unroll
    for (int r = 0; r < 4; ++r) {
      int row = i0 + w * 16 + qr + r;
      catbuf[(size_t)row * 576 + 448 + col] = acc[g][r] + bv;
    }
  }
}

// ---------------------------------------------------------------------------
// Fused EdgeConv A/Pb GEMM
// ---------------------------------------------------------------------------
__global__ __launch_bounds__(256) void edge_gemm_kernel(
    const float* __restrict__ X, int ldx, int D,
    const float* __restrict__ W, int ldw, int M,
    float* __restrict__ A, float* __restrict__ Pb) {
  __shared__ float Xs[16][68];
  __shared__ float Ws[16][68];
  int t = threadIdx.x, tx = t & 15, ty = t >> 4;
  int nHalf = M >> 6;
  int mt = blockIdx.x;
  int is_b = (mt >= nHalf) ? 1 : 0;
  int m0 = (is_b ? mt - nHalf : mt) << 6;
  int koff = is_b ? D : 0;
  float* __restrict__ out = is_b ? Pb : A;
  int i0 = blockIdx.y * 64;
  float acc[4][4];
#pragma unroll
  for (int r = 0; r < 4; ++r)
#pragma unroll
    for (int n = 0; n < 4; ++n) acc[r][n] = 0.f;

  for (int k0 = 0; k0 < D; k0 += 16) {
#pragma unroll
    for (int p = 0; p < 4; ++p) {
      int e = t + p * 256, r = e >> 4, c = e & 15, k = k0 + c;
      Xs[c][r] = (k < D) ? X[(size_t)(i0 + r) * ldx + k] : 0.f;
      Ws[c][r] = (k < D) ? W[(size_t)(m0 + r) * ldw + koff + k] : 0.f;
    }
    __syncthreads();
#pragma unroll
    for (int kk = 0; kk < 16; ++kk) {
      float4 a4 = *(const float4*)&Xs[kk][ty * 4];
      float4 b4 = *(const float4*)&Ws[kk][tx * 4];
      float a[4] = {a4.x, a4.y, a4.z, a4.w};
      float bb[4] = {b4.x, b4.y, b4.z, b4.w};
#pragma unroll
      for (int r = 0; r < 4; ++r)
#pragma unroll
        for (int n = 0; n < 4; ++n) acc[r][n] += a[r] * bb[n];
    }
    __syncthreads();
  }
#pragma unroll
  for (int r = 0; r < 4; ++r) {
    float4 o;
    o.x = acc[r][0]; o.y = acc[r][1]; o.z = acc[r][2]; o.w = acc[r][3];
    *(float4*)&out[(size_t)(i0 + ty * 4 + r) * M + m0 + tx * 4] = o;
  }
}

// ---------------------------------------------------------------------------
// fp32 -> bf16 RNE cast
// ---------------------------------------------------------------------------
__global__ __launch_bounds__(256) void cast_bf16_kernel(
    const float* __restrict__ src, unsigned short* __restrict__ dst, int n) {
  int e4 = (blockIdx.x * 256 + threadIdx.x) * 4;
  if (e4 >= n) return;
  float4 v = *(const float4*)&src[e4];
  ushort4 o;
  unsigned int u;
  u = __float_as_uint(v.x); o.x = (unsigned short)((u + 0x7fff + ((u >> 16) & 1)) >> 16);
  u = __float_as_uint(v.y); o.y = (unsigned short)((u + 0x7fff + ((u >> 16) & 1)) >> 16);
  u = __float_as_uint(v.z); o.z = (unsigned short)((u + 0x7fff + ((u >> 16) & 1)) >> 16);
  u = __float_as_uint(v.w); o.w = (unsigned short)((u + 0x7fff + ((u >> 16) & 1)) >> 16);
  *(ushort4*)&dst[e4] = o;
}

// ---------------------------------------------------------------------------
// hi/lo bf16 split cast + fused sq per row.
// ---------------------------------------------------------------------------
__global__ __launch_bounds__(256) void cast_hl_kernel(
    const float* __restrict__ X, int ldx, int D, int Kp,
    unsigned short* __restrict__ hi, unsigned short* __restrict__ lo,
    float* __restrict__ sq) {
  __shared__ float red[256];
  int i = blockIdx.x;
  int t = threadIdx.x;
  float s = 0.f;
  for (int k = t; k < Kp; k += 256) {
    float x = (k < D) ? X[(size_t)i * ldx + k] : 0.f;
    unsigned int u = __float_as_uint(x);
    unsigned short h = (unsigned short)((u + 0x7fff + ((u >> 16) & 1)) >> 16);
    float hf = __uint_as_float((unsigned int)h << 16);
    float r = x - hf;
    unsigned int v = __float_as_uint(r);
    unsigned short l16 = (unsigned short)((v + 0x7fff + ((v >> 16) & 1)) >> 16);
    hi[(size_t)i * Kp + k] = h;
    lo[(size_t)i * Kp + k] = l16;
    s += x * x;
  }
  red[t] = s;
  __syncthreads();
  for (int off = 128; off > 0; off >>= 1) {
    if (t < off) red[t] += red[t + off];
    __syncthreads();
  }
  if (t == 0) sq[i] = red[0];
}

// ---------------------------------------------------------------------------
// dist_gemm2: bf16 MFMA, 3-pass hi/lo, block tile 128q x 64c (r10-exact).
// ---------------------------------------------------------------------------
template <int KP>
__global__ __launch_bounds__(256) void dist_gemm2_kernel(
    const unsigned short* __restrict__ Xhi,
    const unsigned short* __restrict__ Xlo,
    const float* __restrict__ sq,
    float* __restrict__ dist, int zBase) {
  __shared__ unsigned short Ah[128][40];
  __shared__ unsigned short Al[128][40];
  __shared__ unsigned short Bh[64][40];
  __shared__ unsigned short Bl[64][40];
  int t = threadIdx.x;
  int l = t & 63, w = t >> 6;
  int z = blockIdx.z;
  size_t bbase = (size_t)(zBase + z) * PPB;
  int c0 = blockIdx.x * 64, q0 = blockIdx.y * 128;

  f32x4 acc[2][4];
#pragma unroll
  for (int qs = 0; qs < 2; ++qs)
#pragma unroll
    for (int cc = 0; cc < 4; ++cc) acc[qs][cc] = (f32x4){0.f, 0.f, 0.f, 0.f};

  for (int k0 = 0; k0 < KP; k0 += 32) {
    short8 sa[2][2];
#pragma unroll
    for (int p = 0; p < 2; ++p) {
      int e = t + p * 256, row = e >> 2, kg = e & 3;
      sa[p][0] = *(const short8*)&Xhi[(bbase + q0 + row) * KP + k0 + kg * 8];
      sa[p][1] = *(const short8*)&Xlo[(bbase + q0 + row) * KP + k0 + kg * 8];
    }
    int brow = t >> 2, bkg = t & 3;
    short8 sb0 = *(const short8*)&Xhi[(bbase + c0 + brow) * KP + k0 + bkg * 8];
    short8 sb1 = *(const short8*)&Xlo[(bbase + c0 + brow) * KP + k0 + bkg * 8];
    __syncthreads();
#pragma unroll
    for (int p = 0; p < 2; ++p) {
      int e = t + p * 256, row = e >> 2, kg = e & 3;
      *(short8*)&Ah[row][kg * 8] = sa[p][0];
      *(short8*)&Al[row][kg * 8] = sa[p][1];
    }
    *(short8*)&Bh[brow][bkg * 8] = sb0;
    *(short8*)&Bl[brow][bkg * 8] = sb1;
    __syncthreads();

    bf16x8 ah[2], al[2], bh[4], bl[4];
#pragma unroll
    for (int qs = 0; qs < 2; ++qs) {
      int row = w * 32 + qs * 16 + (l & 15);
      ah[qs] = __builtin_bit_cast(bf16x8, *(const short8*)&Ah[row][(l >> 4) * 8]);
      al[qs] = __builtin_bit_cast(bf16x8, *(const short8*)&Al[row][(l >> 4) * 8]);
    }
#pragma unroll
    for (int cc = 0; cc < 4; ++cc) {
      bh[cc] = __builtin_bit_cast(bf16x8, *(const short8*)&Bh[cc * 16 + (l & 15)][(l >> 4) * 8]);
      bl[cc] = __builtin_bit_cast(bf16x8, *(const short8*)&Bl[cc * 16 + (l & 15)][(l >> 4) * 8]);
    }
#pragma unroll
    for (int qs = 0; qs < 2; ++qs)
#pragma unroll
      for (int cc = 0; cc < 4; ++cc) {
        acc[qs][cc] = __builtin_amdgcn_mfma_f32_16x16x32_bf16(ah[qs], bh[cc], acc[qs][cc], 0, 0, 0);
        acc[qs][cc] = __builtin_amdgcn_mfma_f32_16x16x32_bf16(ah[qs], bl[cc], acc[qs][cc], 0, 0, 0);
        acc[qs][cc] = __builtin_amdgcn_mfma_f32_16x16x32_bf16(al[qs], bh[cc], acc[qs][cc], 0, 0, 0);
      }
  }
  float* dz = dist + (size_t)z * PPB * PPB;
#pragma unroll
  for (int cc = 0; cc < 4; ++cc) {
    int j = c0 + cc * 16 + (l & 15);
    float sqj = sq[bbase + j];
#pragma unroll
    for (int qs = 0; qs < 2; ++qs) {
      int qb = q0 + w * 32 + qs * 16 + (l >> 4) * 4;
#pragma unroll
      for (int r = 0; r < 4; ++r)
        dz[(size_t)(qb + r) * PPB + j] = sqj - 2.f * acc[qs][cc][r];
    }
  }
}

// ---------------------------------------------------------------------------
// knn_sel6: sel3's structure with LAZY PER-LANE TOP-2.
// One wave/row; lane owns j = lane*32+m.  Upfront ascending strict-< scan
// gives (v1,m1),(v2,m2) exact (lowest index on ties).  Extraction: packed
// u64 butterfly (ordered dist key | j) = exact (dist asc, lowest j).
// On win: promote v2->v1 (cheap); on a lane's SECOND win: full masked
// rescan (expected ~3 lanes/row).  Selection set identical to sel3.
// grid (PPB/4, nz).
// ---------------------------------------------------------------------------
__global__ __launch_bounds__(256) void knn_sel6_kernel(
    const float* __restrict__ dist, int zBase, int* __restrict__ idx) {
  int z = blockIdx.y;
  int b = zBase + z;
  int q = blockIdx.x * 4 + (threadIdx.x >> 6);
  int lane = threadIdx.x & 63;
  const float* row = dist + ((size_t)z * PPB + q) * PPB + lane * 32;

  float v[32];
#pragma unroll
  for (int m4 = 0; m4 < 8; ++m4) {
    float4 f = *(const float4*)&row[m4 * 4];
    v[m4 * 4 + 0] = f.x; v[m4 * 4 + 1] = f.y;
    v[m4 * 4 + 2] = f.z; v[m4 * 4 + 3] = f.w;
  }
  // initial exact top-2 (ascending, strict <)
  float v1 = 1e38f, v2 = 1e38f;
  int m1 = 0, m2 = 0;
#pragma unroll
  for (int m = 0; m < 32; ++m) {
    float x = v[m];
    if (x < v1) { v2 = v1; m2 = m1; v1 = x; m1 = m; }
    else if (x < v2) { v2 = x; m2 = m; }
  }
  bool have2 = true;
  unsigned rm = 0;

#pragma unroll
  for (int s = 0; s < KNN; ++s) {
    unsigned u = __float_as_uint(v1);
    unsigned key = u ^ (((int)u >> 31) | 0x80000000u);
    unsigned long long p =
        ((unsigned long long)key << 32) | (unsigned)(lane * 32 + m1);
#pragma unroll
    for (int o = 1; o < 64; o <<= 1) {
      unsigned long long t2 = __shfl_xor(p, o);
      if (t2 < p) p = t2;
    }
    unsigned j = (unsigned)p;
    if (lane == 0)
      idx[((size_t)b * PPB + q) * KNN + s] = b * PPB + (int)j;
    if ((j >> 5) == (unsigned)lane) {
      rm |= 1u << (j & 31u);
      if (have2) {
        v1 = v2; m1 = m2;
        have2 = false;
      } else {
        // full masked rescan (rare): exact top-2 of remaining
        v1 = 1e38f; v2 = 1e38f; m1 = 0; m2 = 0;
#pragma unroll
        for (int m = 0; m < 32; ++m) {
          float x = ((rm >> m) & 1u) ? 1e38f : v[m];
          if (x < v1) { v2 = v1; m2 = m1; v1 = x; m1 = m; }
          else if (x < v2) { v2 = x; m2 = m; }
        }
        have2 = true;
      }
    }
  }
}

// ---------------------------------------------------------------------------
// fc1 (576 -> 1024) via bf16 MFMA, fused max over 64-point tile.
// ---------------------------------------------------------------------------
__global__ __launch_bounds__(256) void fc1max_mfma_kernel(
    const unsigned short* __restrict__ Xb, const unsigned short* __restrict__ Wb,
    const float* __restrict__ bias, float* __restrict__ partial) {
  __shared__ unsigned short Xs[64][40];
  __shared__ unsigned short Ws[64][40];
  __shared__ float red[4][64];
  int t = threadIdx.x;
  int l = t & 63, w = t >> 6;
  int b = blockIdx.z, pt = blockIdx.y;
  int i0 = b * PPB + pt * 64;
  int m0 = blockIdx.x * 64;
  int r_st = t >> 2;
  int c_st = (t & 3) * 8;

  f32x4 acc[4];
#pragma unroll
  for (int g = 0; g < 4; ++g) acc[g] = (f32x4){0.f, 0.f, 0.f, 0.f};

  for (int k0 = 0; k0 < 576; k0 += 32) {
    short8 xv = *(const short8*)&Xb[(size_t)(i0 + r_st) * 576 + k0 + c_st];
    short8 wv = *(const short8*)&Wb[(size_t)(m0 + r_st) * 576 + k0 + c_st];
    __syncthreads();
    *(short8*)&Xs[r_st][c_st] = xv;
    *(short8*)&Ws[r_st][c_st] = wv;
    __syncthreads();
    short8 ar = *(const short8*)&Xs[16 * w + (l & 15)][(l >> 4) * 8];
    bf16x8 av = __builtin_bit_cast(bf16x8, ar);
#pragma unroll
    for (int g = 0; g < 4; ++g) {
      short8 br = *(const short8*)&Ws[g * 16 + (l & 15)][(l >> 4) * 8];
      bf16x8 bv = __builtin_bit_cast(bf16x8, br);
      acc[g] = __builtin_amdgcn_mfma_f32_16x16x32_bf16(av, bv, acc[g], 0, 0, 0);
    }
  }
  float pm[4];
#pragma unroll
  for (int g = 0; g < 4; ++g) {
    float m = fmaxf(fmaxf(acc[g][0], acc[g][1]), fmaxf(acc[g][2], acc[g][3]));
    m = fmaxf(m, __shfl_xor(m, 16));
    m = fmaxf(m, __shfl_xor(m, 32));
    pm[g] = m;
  }
  if (l < 16) {
#pragma unroll
    for (int g = 0; g < 4; ++g) red[w][g * 16 + l] = pm[g];
  }
  __syncthreads();
  if (t < 64) {
    float mx = fmaxf(fmaxf(red[0][t], red[1][t]), fmaxf(red[2][t], red[3][t]));
    partial[((size_t)b * (PPB / 64) + pt) * 1024 + m0 + t] = mx + bias[m0 + t];
  }
}

__global__ __launch_bounds__(256) void gmax_kernel(
    const float* __restrict__ partial, float* __restrict__ g) {
  int b = blockIdx.y;
  int m = blockIdx.x * 256 + threadIdx.x;
  float mx = -INFINITY;
  for (int pt = 0; pt < PPB / 64; ++pt)
    mx = fmaxf(mx, partial[((size_t)b * (PPB / 64) + pt) * 1024 + m]);
  g[b * 1024 + m] = mx;
}

// ---------------------------------------------------------------------------
__global__ __launch_bounds__(192) void h0_kernel(
    const float* __restrict__ pos, const float* __restrict__ xin,
    const float* __restrict__ catbuf, float* __restrict__ h0) {
  int i = blockIdx.x;
  int d = threadIdx.x;
  if (d < 3)        h0[(size_t)i * 134 + d] = pos[i * 3 + d];
  else if (d < 6)   h0[(size_t)i * 134 + d] = xin[i * 3 + d - 3];
  else if (d < 134) h0[(size_t)i * 134 + d] = catbuf[(size_t)i * 576 + 448 + (d - 6)];
}

// ---------------------------------------------------------------------------
// EdgeConv epilogue
// ---------------------------------------------------------------------------
__global__ __launch_bounds__(256) void edge_out_kernel(
    const float* __restrict__ A, const float* __restrict__ Pb, int M,
    const float* __restrict__ bias, const int* __restrict__ idx,
    float* __restrict__ Y, int ldy) {
  int i = blockIdx.x;
  int t = threadIdx.x;
  __shared__ int nbs[KNN];
  if (t < KNN) nbs[t] = idx[(size_t)i * KNN + t];
  __syncthreads();
  for (int m = t; m < M; m += 256) {
    float mx = -INFINITY;
#pragma unroll
    for (int kk = 0; kk < KNN; ++kk)
      mx = fmaxf(mx, Pb[(size_t)nbs[kk] * M + m]);
    Y[(size_t)i * ldy + m] = A[(size_t)i * M + m] + bias[m] - Pb[(size_t)i * M + m] + mx;
  }
}

// ---------------------------------------------------------------------------
// mlp2: wave-per-output GEMV.
// ---------------------------------------------------------------------------
__global__ __launch_bounds__(256) void mlp2_kernel(
    const float* __restrict__ X, const float* __restrict__ W,
    const float* __restrict__ bias, float* __restrict__ Y,
    int D, int M, int do_relu) {
  int b = blockIdx.y;
  int m = blockIdx.x * 4 + (threadIdx.x >> 6);
  int lane = threadIdx.x & 63;
  const float* xr = X + (size_t)b * D;
  const float* wr = W + (size_t)m * D;
  float s = 0.f;
  for (int k = lane * 4; k < D; k += 256) {
    float4 xv = *(const float4*)&xr[k];
    float4 wv = *(const float4*)&wr[k];
    s += xv.x * wv.x + xv.y * wv.y + xv.z * wv.z + xv.w * wv.w;
  }
#pragma unroll
  for (int o = 32; o > 0; o >>= 1) s += __shfl_down(s, o);
  if (lane == 0) {
    s += bias[m];
    if (do_relu) s = fmaxf(s, 0.f);
    Y[(size_t)b * M + m] = s;
  }
}

// ---------------------------------------------------------------------------
// final2: wave-parallel 256->23 + log_softmax.
// ---------------------------------------------------------------------------
__global__ __launch_bounds__(256) void final2_kernel(
    const float* __restrict__ X, const float* __restrict__ W,
    const float* __restrict__ bias, float* __restrict__ out) {
  int b = blockIdx.x;
  int w = threadIdx.x >> 6, lane = threadIdx.x & 63;
  __shared__ float lg[23];
  const float* xr = X + (size_t)b * 256;
  float4 xv = *(const float4*)&xr[lane * 4];
  for (int c = w; c < 23; c += 4) {
    const float* wr = W + (size_t)c * 256;
    float4 wv = *(const float4*)&wr[lane * 4];
    float s = xv.x * wv.x + xv.y * wv.y + xv.z * wv.z + xv.w * wv.w;
#pragma unroll
    for (int o = 32; o > 0; o >>= 1) s += __shfl_down(s, o);
    if (lane == 0) lg[c] = s + bias[c];
  }
  __syncthreads();
  if (threadIdx.x == 0) {
    float mx = lg[0];
    for (int c = 1; c < 23; ++c) mx = fmaxf(mx, lg[c]);
    float s = 0.f;
    for (int c = 0; c < 23; ++c) s += expf(lg[c] - mx);
    float lse = mx + logf(s);
    for (int c = 0; c < 23; ++c) out[b * 23 + c] = lg[c] - lse;
  }
}

// ---------------------------------------------------------------------------

extern "C" void kernel_launch(void* const* d_in, const int* in_sizes, int n_in,
                              void* d_out, int out_size, void* d_ws, size_t ws_size,
                              hipStream_t stream) {
  const float* pos      = (const float*)d_in[0];
  const float* xin      = (const float*)d_in[1];
  const float* features = (const float*)d_in[2];
  const float* Wf   = (const float*)d_in[4];
  const float* bf   = (const float*)d_in[5];
  const float* W1   = (const float*)d_in[6];
  const float* b1   = (const float*)d_in[7];
  const float* W2   = (const float*)d_in[8];
  const float* b2   = (const float*)d_in[9];
  const float* W3   = (const float*)d_in[10];
  const float* b3   = (const float*)d_in[11];
  const float* Wfc1 = (const float*)d_in[12];
  const float* bfc1 = (const float*)d_in[13];
  const float* Wfa  = (const float*)d_in[14];
  const float* bfa  = (const float*)d_in[15];
  const float* Wfb  = (const float*)d_in[16];
  const float* bfb  = (const float*)d_in[17];
  const float* Wfc  = (const float*)d_in[18];
  const float* bfc  = (const float*)d_in[19];
  float* out = (float*)d_out;

  const int N = in_sizes[0] / 3;  // 16384

  char* base = (char*)d_ws;
  size_t off = 0;
  auto alloc = [&](size_t bytes) {
    void* p = base + off;
    off += (bytes + 255) & ~(size_t)255;
    return p;
  };
  float* catbuf  = (float*)alloc((size_t)N * 576 * 4);  // [x1|x2|x3|feats]
  float* h0      = (float*)alloc((size_t)N * 134 * 4);
  float* Abuf    = (float*)alloc((size_t)N * 256 * 4);
  float* Pbbuf   = (float*)alloc((size_t)N * 256 * 4);
  unsigned short* Xhi = (unsigned short*)alloc((size_t)N * 160 * 2);
  unsigned short* Xlo = (unsigned short*)alloc((size_t)N * 160 * 2);
  float* sqbuf   = (float*)alloc((size_t)N * 4);
  int*   idxbuf  = (int*)  alloc((size_t)N * KNN * 4);
  float* partial = (float*)alloc((size_t)NBATCH * (PPB / 64) * 1024 * 4);
  float* g       = (float*)alloc((size_t)NBATCH * 1024 * 4);
  float* ga      = (float*)alloc((size_t)NBATCH * 512 * 4);
  float* gb      = (float*)alloc((size_t)NBATCH * 256 * 4);

  // dist chunking: nz=8 (r10 best).  Fallbacks keep correctness on small ws.
  const size_t distBatch = (size_t)PPB * PPB * 4;
  int nz;
  float* dist;
  if (ws_size >= off + 8 * distBatch + 256) {
    nz = 8;  dist = (float*)alloc(8 * distBatch);
  } else if (ws_size >= off + 4 * distBatch + 256) {
    nz = 4;  dist = (float*)alloc(4 * distBatch);
  } else {
    nz = 2;  dist = Abuf;
  }

  float* fpart = Abuf;
  unsigned short* catb16 = (unsigned short*)Abuf;
  unsigned short* Wb16   = (unsigned short*)h0;

  // 1. feats = features @ Wf.T + bf -> catbuf[:,448:576]
  if (nz == 8) {
    unsigned short* featHi = (unsigned short*)dist;
    unsigned short* featLo = featHi + (size_t)N * 1344;
    unsigned short* WfHi   = (unsigned short*)partial;
    unsigned short* WfLo   = WfHi + (size_t)128 * 1344;
    cast_hl_kernel<<<N, 256, 0, stream>>>(features, 1344, 1344, 1344,
                                          featHi, featLo, sqbuf);
    cast_hl_kernel<<<128, 256, 0, stream>>>(Wf, 1344, 1344, 1344,
                                            WfHi, WfLo, sqbuf);
    feats_mfma_kernel<<<dim3(2, N / 64), 256, 0, stream>>>(
        featHi, featLo, WfHi, WfLo, bf, catbuf);
  } else {
    gemm_feats_kernel<<<dim3(1, N / 128, 4), 256, 0, stream>>>(features, Wf, fpart, N);
    reduce_feats_kernel<<<(N * 128) / 256, 256, 0, stream>>>(fpart, bf, catbuf, N);
  }

  // 2. h0 = [pos | x | feats]
  h0_kernel<<<N, 192, 0, stream>>>(pos, xin, catbuf, h0);

  struct Layer {
    const float* Xin; int ldx; int D; int Kp;
    const float* W; int ldw;
    const float* bias; int M;
    float* Yout;
  };
  Layer L[3] = {
      {h0,          134, 134, 160, W1, 268, b1,  64, catbuf + 0},
      {catbuf + 0,  576,  64,  64, W2, 128, b2, 128, catbuf + 64},
      {catbuf + 64, 576, 128, 128, W3, 256, b3, 256, catbuf + 192},
  };

  for (int l = 0; l < 3; ++l) {
    cast_hl_kernel<<<N, 256, 0, stream>>>(L[l].Xin, L[l].ldx, L[l].D, L[l].Kp,
                                          Xhi, Xlo, sqbuf);
    for (int p = 0; p < NBATCH; p += nz) {
      if (L[l].Kp == 160)
        dist_gemm2_kernel<160><<<dim3(PPB / 64, PPB / 128, nz), 256, 0, stream>>>(
            Xhi, Xlo, sqbuf, dist, p);
      else if (L[l].Kp == 64)
        dist_gemm2_kernel<64><<<dim3(PPB / 64, PPB / 128, nz), 256, 0, stream>>>(
            Xhi, Xlo, sqbuf, dist, p);
      else
        dist_gemm2_kernel<128><<<dim3(PPB / 64, PPB / 128, nz), 256, 0, stream>>>(
            Xhi, Xlo, sqbuf, dist, p);
      knn_sel6_kernel<<<dim3(PPB / 4, nz), 256, 0, stream>>>(dist, p, idxbuf);
    }
    // fused A = X@Wa.T and Pb = X@Wb.T
    edge_gemm_kernel<<<dim3((2 * L[l].M) / 64, N / 64), 256, 0, stream>>>(
        L[l].Xin, L[l].ldx, L[l].D, L[l].W, L[l].ldw, L[l].M, Abuf, Pbbuf);
    edge_out_kernel<<<N, 256, 0, stream>>>(
        Abuf, Pbbuf, L[l].M, L[l].bias, idxbuf, L[l].Yout, 576);
  }

  // casts for fc1 (catbuf complete; Abuf/Pbbuf/h0 dead)
  cast_bf16_kernel<<<(N * 576) / 1024, 256, 0, stream>>>(catbuf, catb16, N * 576);
  cast_bf16_kernel<<<(1024 * 576) / 1024, 256, 0, stream>>>(Wfc1, Wb16, 1024 * 576);

  // fc1 + max over points (bf16 MFMA)
  fc1max_mfma_kernel<<<dim3(1024 / 64, PPB / 64, NBATCH), 256, 0, stream>>>(
      catb16, Wb16, bfc1, partial);
  gmax_kernel<<<dim3(1024 / 256, NBATCH), 256, 0, stream>>>(partial, g);

  // head MLP (wave-per-output GEMV)
  mlp2_kernel<<<dim3(512 / 4, NBATCH), 256, 0, stream>>>(g,  Wfa, bfa, ga, 1024, 512, 1);
  mlp2_kernel<<<dim3(256 / 4, NBATCH), 256, 0, stream>>>(ga, Wfb, bfb, gb, 512, 256, 1);
  final2_kernel<<<NBATCH, 256, 0, stream>>>(gb, Wfc, bfc, out);
}